// Round 11
// baseline (842.401 us; speedup 1.0000x reference)
//
#include <hip/hip_runtime.h>
#include <math.h>

#define DD     512
#define NBATCH 16
#define SENC   1024
#define TTOK   2048
#define NHEAD  8
#define HDIM   64
#define NE     64

// ---------------- workspace layout (float element offsets) ----------------
#define WS_K1    0                           // 16*1024*512
#define WS_V1    (WS_K1 + NBATCH*SENC*DD)
#define WS_EMB0  (WS_V1 + NBATCH*SENC*DD)    // 64*512
#define WS_Q1    (WS_EMB0 + NE*DD)
#define WS_ATT1  (WS_Q1 + NE*DD)             // 16*64*512
#define WS_EMB1  (WS_ATT1 + NBATCH*NE*DD)
#define WS_Q2    (WS_EMB1 + NBATCH*NE*DD)
#define WS_K2    (WS_Q2 + NBATCH*NE*DD)
#define WS_V2    (WS_K2 + NBATCH*NE*DD)
#define WS_ATT2  (WS_V2 + NBATCH*NE*DD)
#define WS_YBUF  (WS_ATT2 + NBATCH*NE*DD)
#define WS_EMBF  (WS_YBUF + NBATCH*NE*DD)
#define WS_E2    (WS_EMBF + NBATCH*NE*DD)    // doubles: 16*64  (=2048 floats)
#define WS_LOSSP (WS_E2 + 2*NBATCH*NE)       // doubles: 512    (=1024 floats)
#define WS_CNT   (WS_LOSSP + 2*512)          // ints: 64

// ---------------- output layout (float element offsets) ----------------
#define OUT_ZQ   0
#define OUT_LOSS (NBATCH*TTOK*DD)            // 16777216
#define OUT_PERP (OUT_LOSS + 1)
#define OUT_ENC  (OUT_PERP + 1)
#define OUT_IDX  (OUT_ENC + NBATCH*TTOK*NE)
#define OUT_EMB  (OUT_IDX + NBATCH*TTOK)

// =======================================================================
// PE + emb0  (UNCHANGED — stage A must stay bit-identical)
// =======================================================================
__global__ __launch_bounds__(256) void pe_emb0_k(const float* __restrict__ tab,
                                                 float* __restrict__ emb0)
{
    int p = blockIdx.x;
    for (int c = threadIdx.x; c < DD; c += 256) {
        int ie = c & ~1;
        float denom = (float)pow(10000.0, (double)ie / 512.0);
        float ang = (float)p / denom;            // f32 division, matches np
        double v = (c & 1) ? cos((double)ang) : sin((double)ang);
        emb0[p * DD + c] = tab[p * DD + c] + (float)v;
    }
}

// =======================================================================
// q1 projection, round 11: the old gemm_bias<1> grid(1,8) used 8 blocks
// (3% of GPU, pure latency ~23us). New: 128 blocks x 256 threads, thread
// = one output element; lane = column (coalesced W reads), A row is
// wave-uniform broadcast. Ascending-k fmaf chain + bias at end ->
// bit-identical to the old kernel's q1.
// =======================================================================
__global__ __launch_bounds__(256) void gemm_q1_k(
    const float* __restrict__ A, const float* __restrict__ W,
    const float* __restrict__ B, float* __restrict__ C)
{
    const int rg   = blockIdx.x >> 3;          // 16 row-groups of 4
    const int c0   = (blockIdx.x & 7) * 64;
    const int ri   = threadIdx.x >> 6;         // 0..3
    const int lane = threadIdx.x & 63;
    const int row  = rg * 4 + ri;
    const float* Ar = A + (size_t)row * DD;
    const float* Wc = W + c0 + lane;
    float acc = 0.f;
#pragma unroll 8
    for (int k = 0; k < DD; ++k)
        acc = fmaf(Ar[k], Wc[(size_t)k * DD], acc);
    C[(size_t)row * DD + c0 + lane] = acc + B[c0 + lane];
}

// =======================================================================
// Big-M GEMM (K/V projection) — UNCHANGED (measured 218 us best-of-4).
// =======================================================================
__global__ __launch_bounds__(256) void gemm_kv_k(
    const float* __restrict__ A,
    const float* __restrict__ W0, const float* __restrict__ B0, float* __restrict__ C0,
    const float* __restrict__ W1, const float* __restrict__ B1, float* __restrict__ C1)
{
    __shared__ float As[32][260];       // [k][m] 256 rows + pad
    __shared__ float Ws[2][32][68];     // [k][n]
    const int bid = blockIdx.x;
    const int xcd = bid & 7;
    const int idx = bid >> 3;
    const int m0 = (xcd * 8 + (idx >> 3)) * 256;
    const int n0 = (idx & 7) * 64;
    const int tid = threadIdx.x;
    const int tx = tid & 15, ty = tid >> 4;   // tx: 4 n-cols, ty: 16 m-rows

    float acc[2][16][4];
#pragma unroll
    for (int o = 0; o < 2; ++o)
#pragma unroll
        for (int i = 0; i < 16; ++i)
#pragma unroll
            for (int j = 0; j < 4; ++j) acc[o][i][j] = 0.f;

    for (int kk = 0; kk < DD; kk += 32) {
        __syncthreads();
#pragma unroll
        for (int l = 0; l < 8; ++l) {             // A: 2048 float4
            int fid = l * 256 + tid;
            int row = fid >> 3, c4 = fid & 7;
            float4 v = *reinterpret_cast<const float4*>(&A[(size_t)(m0 + row) * DD + kk + c4 * 4]);
            As[c4 * 4 + 0][row] = v.x;
            As[c4 * 4 + 1][row] = v.y;
            As[c4 * 4 + 2][row] = v.z;
            As[c4 * 4 + 3][row] = v.w;
        }
        {
            int kr = tid >> 4, c4 = tid & 15;     // W: 512 float4 per output
            *reinterpret_cast<float4*>(&Ws[0][kr][c4 * 4]) =
                *reinterpret_cast<const float4*>(&W0[(size_t)(kk + kr) * DD + n0 + c4 * 4]);
            *reinterpret_cast<float4*>(&Ws[0][kr + 16][c4 * 4]) =
                *reinterpret_cast<const float4*>(&W0[(size_t)(kk + kr + 16) * DD + n0 + c4 * 4]);
            *reinterpret_cast<float4*>(&Ws[1][kr][c4 * 4]) =
                *reinterpret_cast<const float4*>(&W1[(size_t)(kk + kr) * DD + n0 + c4 * 4]);
            *reinterpret_cast<float4*>(&Ws[1][kr + 16][c4 * 4]) =
                *reinterpret_cast<const float4*>(&W1[(size_t)(kk + kr + 16) * DD + n0 + c4 * 4]);
        }
        __syncthreads();
#pragma unroll 4
        for (int k = 0; k < 32; ++k) {
            float4 a0 = *reinterpret_cast<const float4*>(&As[k][ty * 16]);
            float4 a1 = *reinterpret_cast<const float4*>(&As[k][ty * 16 + 4]);
            float4 a2 = *reinterpret_cast<const float4*>(&As[k][ty * 16 + 8]);
            float4 a3 = *reinterpret_cast<const float4*>(&As[k][ty * 16 + 12]);
            float a[16] = {a0.x, a0.y, a0.z, a0.w, a1.x, a1.y, a1.z, a1.w,
                           a2.x, a2.y, a2.z, a2.w, a3.x, a3.y, a3.z, a3.w};
            float4 w0 = *reinterpret_cast<const float4*>(&Ws[0][k][tx * 4]);
            float4 w1 = *reinterpret_cast<const float4*>(&Ws[1][k][tx * 4]);
#pragma unroll
            for (int i = 0; i < 16; ++i) {
                acc[0][i][0] = fmaf(a[i], w0.x, acc[0][i][0]);
                acc[0][i][1] = fmaf(a[i], w0.y, acc[0][i][1]);
                acc[0][i][2] = fmaf(a[i], w0.z, acc[0][i][2]);
                acc[0][i][3] = fmaf(a[i], w0.w, acc[0][i][3]);
                acc[1][i][0] = fmaf(a[i], w1.x, acc[1][i][0]);
                acc[1][i][1] = fmaf(a[i], w1.y, acc[1][i][1]);
                acc[1][i][2] = fmaf(a[i], w1.z, acc[1][i][2]);
                acc[1][i][3] = fmaf(a[i], w1.w, acc[1][i][3]);
            }
        }
    }
    float* Cp[2] = {C0, C1};
    const float* Bp[2] = {B0, B1};
#pragma unroll
    for (int o = 0; o < 2; ++o) {
        float4 bv = *reinterpret_cast<const float4*>(&Bp[o][n0 + tx * 4]);
#pragma unroll
        for (int i = 0; i < 16; ++i) {
            int row = m0 + ty * 16 + i;
            float4 o4 = {acc[o][i][0] + bv.x, acc[o][i][1] + bv.y,
                         acc[o][i][2] + bv.z, acc[o][i][3] + bv.w};
            *reinterpret_cast<float4*>(&Cp[o][(size_t)row * DD + n0 + tx * 4]) = o4;
        }
    }
}

// =======================================================================
// Generic f32 GEMM + bias (UNCHANGED — used for small-M GEMMs)
// =======================================================================
template <int NOUT>
__global__ __launch_bounds__(256) void gemm_bias_k(
    const float* __restrict__ A,
    const float* __restrict__ W0, const float* __restrict__ B0, float* __restrict__ C0,
    const float* __restrict__ W1, const float* __restrict__ B1, float* __restrict__ C1,
    const float* __restrict__ W2, const float* __restrict__ B2, float* __restrict__ C2)
{
    __shared__ float As[32][64];          // [k][m]
    __shared__ float Ws[NOUT][32][64];    // [k][n]
    const int m0 = blockIdx.x * 64;
    const int n0 = blockIdx.y * 64;
    const int tid = threadIdx.x;
    const int tx = tid & 15, ty = tid >> 4;

    float acc[NOUT][4][4];
#pragma unroll
    for (int o = 0; o < NOUT; ++o)
#pragma unroll
        for (int i = 0; i < 4; ++i)
#pragma unroll
            for (int j = 0; j < 4; ++j) acc[o][i][j] = 0.f;

    const float* Wp[3] = {W0, W1, W2};

    for (int kk = 0; kk < DD; kk += 32) {
        __syncthreads();
#pragma unroll
        for (int l = 0; l < 2; ++l) {
            int fid = l * 256 + tid;          // 512 float4 of A tile
            int row = fid >> 3, c4 = fid & 7;
            float4 v = *reinterpret_cast<const float4*>(&A[(size_t)(m0 + row) * DD + kk + c4 * 4]);
            As[c4 * 4 + 0][row] = v.x;
            As[c4 * 4 + 1][row] = v.y;
            As[c4 * 4 + 2][row] = v.z;
            As[c4 * 4 + 3][row] = v.w;
        }
#pragma unroll
        for (int o = 0; o < NOUT; ++o) {
#pragma unroll
            for (int l = 0; l < 2; ++l) {
                int fid = l * 256 + tid;      // 512 float4 of W tile
                int kr = fid >> 4, c4 = fid & 15;
                *reinterpret_cast<float4*>(&Ws[o][kr][c4 * 4]) =
                    *reinterpret_cast<const float4*>(&Wp[o][(size_t)(kk + kr) * DD + n0 + c4 * 4]);
            }
        }
        __syncthreads();
#pragma unroll
        for (int k = 0; k < 32; ++k) {
            float4 av = *reinterpret_cast<const float4*>(&As[k][ty * 4]);
            float a[4] = {av.x, av.y, av.z, av.w};
#pragma unroll
            for (int o = 0; o < NOUT; ++o) {
                float4 wv = *reinterpret_cast<const float4*>(&Ws[o][k][tx * 4]);
#pragma unroll
                for (int i = 0; i < 4; ++i) {
                    acc[o][i][0] = fmaf(a[i], wv.x, acc[o][i][0]);
                    acc[o][i][1] = fmaf(a[i], wv.y, acc[o][i][1]);
                    acc[o][i][2] = fmaf(a[i], wv.z, acc[o][i][2]);
                    acc[o][i][3] = fmaf(a[i], wv.w, acc[o][i][3]);
                }
            }
        }
    }
    float* Cp[3] = {C0, C1, C2};
    const float* Bp[3] = {B0, B1, B2};
#pragma unroll
    for (int o = 0; o < NOUT; ++o) {
#pragma unroll
        for (int i = 0; i < 4; ++i) {
            int row = m0 + ty * 4 + i;
#pragma unroll
            for (int j = 0; j < 4; ++j) {
                int col = n0 + tx * 4 + j;
                Cp[o][(size_t)row * DD + col] = acc[o][i][j] + Bp[o][col];
            }
        }
    }
}

// =======================================================================
// MHA core, round 11: V comes straight from global (L1-resident — each
// tile's V rows are 16KB, read as quad-broadcast b128s at VMEM issue
// rate), so the vs LDS buffer and its staging writes are gone (LDS
// 47K->28K, 5 blocks/CU). K staging unchanged (plain [64][68]).
// Same values, same fmaf order -> bit-identical outputs.
// =======================================================================
__global__ __launch_bounds__(128) void attn_k(
    const float* __restrict__ q, int q_shared,
    const float* __restrict__ kmat, const float* __restrict__ vmat,
    float* __restrict__ outp, int slen)
{
    __shared__ float qs[32][68];
    __shared__ float kst[64][68]; // [e][j] (transposed)
    int bid = blockIdx.x;
    int b = bid >> 4, h = (bid >> 1) & 7, half = bid & 1;
    int tid = threadIdx.x;
    const float* qb = q + (q_shared ? (size_t)0 : (size_t)b * 64 * DD);
    const float* kb = kmat + (size_t)b * slen * DD;
    const float* vb = vmat + (size_t)b * slen * DD;

#pragma unroll
    for (int l = 0; l < 4; ++l) {               // 32 rows x 16 float4
        int fid = l * 128 + tid;
        int r = fid >> 4, c4 = fid & 15;
        *reinterpret_cast<float4*>(&qs[r][c4 * 4]) =
            *reinterpret_cast<const float4*>(&qb[(size_t)(half * 32 + r) * DD + h * HDIM + c4 * 4]);
    }
    const int row = tid >> 2, c4 = tid & 3;     // row 0..31
    float acc[16];
#pragma unroll
    for (int i = 0; i < 16; ++i) acc[i] = 0.f;
    float m_run = -INFINITY, l_run = 0.f;

    for (int s0 = 0; s0 < slen; s0 += 64) {
        __syncthreads();
#pragma unroll
        for (int l = 0; l < 8; ++l) {           // K only: 64 rows x 16 float4
            int fid = l * 128 + tid;
            int r = fid >> 4, cc = fid & 15;
            float4 t4 = *reinterpret_cast<const float4*>(&kb[(size_t)(s0 + r) * DD + h * HDIM + cc * 4]);
            kst[cc * 4 + 0][r] = t4.x;
            kst[cc * 4 + 1][r] = t4.y;
            kst[cc * 4 + 2][r] = t4.z;
            kst[cc * 4 + 3][r] = t4.w;
        }
        __syncthreads();

        float p[16];
#pragma unroll
        for (int i = 0; i < 16; ++i) p[i] = 0.f;
#pragma unroll 4
        for (int e = 0; e < 64; ++e) {
            float qv = qs[row][e];
#pragma unroll
            for (int j4 = 0; j4 < 4; ++j4) {
                float4 k4 = *reinterpret_cast<const float4*>(&kst[e][c4 * 16 + j4 * 4]);
                p[j4 * 4 + 0] = fmaf(qv, k4.x, p[j4 * 4 + 0]);
                p[j4 * 4 + 1] = fmaf(qv, k4.y, p[j4 * 4 + 1]);
                p[j4 * 4 + 2] = fmaf(qv, k4.z, p[j4 * 4 + 2]);
                p[j4 * 4 + 3] = fmaf(qv, k4.w, p[j4 * 4 + 3]);
            }
        }
#pragma unroll
        for (int i = 0; i < 16; ++i) p[i] *= 0.125f;   // / sqrt(64), exact
        float mx = p[0];
#pragma unroll
        for (int i = 1; i < 16; ++i) mx = fmaxf(mx, p[i]);
        mx = fmaxf(mx, __shfl_xor(mx, 1));
        mx = fmaxf(mx, __shfl_xor(mx, 2));
        float m_new = fmaxf(m_run, mx);
        float scale = expf(m_run - m_new);             // 0 on first tile
        float lsum = 0.f;
#pragma unroll
        for (int i = 0; i < 16; ++i) { p[i] = expf(p[i] - m_new); lsum += p[i]; }
        lsum += __shfl_xor(lsum, 1);
        lsum += __shfl_xor(lsum, 2);
        l_run = l_run * scale + lsum;
        m_run = m_new;
#pragma unroll
        for (int i = 0; i < 16; ++i) acc[i] *= scale;

        const float* vt = vb + (size_t)s0 * DD + h * HDIM + c4 * 16;
#pragma unroll 16
        for (int j = 0; j < 64; ++j) {
            float pv = __shfl(p[j & 15], j >> 4, 4);   // owner lane in quad
            const float* vj = vt + (size_t)j * DD;
#pragma unroll
            for (int u = 0; u < 4; ++u) {
                float4 v4 = *reinterpret_cast<const float4*>(&vj[u * 4]);
                acc[u * 4 + 0] = fmaf(pv, v4.x, acc[u * 4 + 0]);
                acc[u * 4 + 1] = fmaf(pv, v4.y, acc[u * 4 + 1]);
                acc[u * 4 + 2] = fmaf(pv, v4.z, acc[u * 4 + 2]);
                acc[u * 4 + 3] = fmaf(pv, v4.w, acc[u * 4 + 3]);
            }
        }
    }
#pragma unroll
    for (int i = 0; i < 16; ++i) acc[i] /= l_run;
#pragma unroll
    for (int u = 0; u < 4; ++u) {
        float4 o4 = {acc[u * 4 + 0], acc[u * 4 + 1], acc[u * 4 + 2], acc[u * 4 + 3]};
        *reinterpret_cast<float4*>(&outp[((size_t)b * 64 + half * 32 + row) * DD + h * HDIM + c4 * 16 + u * 4]) = o4;
    }
}

// =======================================================================
// LayerNorm (UNCHANGED)
// =======================================================================
__device__ __forceinline__ float block_sum256(float v, float* sb)
{
#pragma unroll
    for (int off = 32; off; off >>= 1) v += __shfl_down(v, off);
    __syncthreads();
    if ((threadIdx.x & 63) == 0) sb[threadIdx.x >> 6] = v;
    __syncthreads();
    return (sb[0] + sb[1]) + (sb[2] + sb[3]);
}

__global__ __launch_bounds__(256) void ln_k(
    const float* __restrict__ res, int res_shared, const float* __restrict__ y,
    const float* __restrict__ g, const float* __restrict__ bb,
    float* __restrict__ out, float* __restrict__ out2, double* __restrict__ e2)
{
    __shared__ float sbuf[4];
    __shared__ double dbuf[4];
    int row = blockIdx.x;
    int t = threadIdx.x;
    const float* rp = res + (size_t)(res_shared ? (row & 63) : row) * DD;
    const float* yp = y + (size_t)row * DD;
    float x0 = rp[t] + yp[t];
    float x1 = rp[t + 256] + yp[t + 256];
    float m = block_sum256(x0 + x1, sbuf) / 512.0f;
    float d0 = x0 - m, d1 = x1 - m;
    float v = block_sum256(d0 * d0 + d1 * d1, sbuf) / 512.0f;
    float s = sqrtf(v + 1e-5f);
    float o0 = d0 / s * g[t] + bb[t];
    float o1 = d1 / s * g[t + 256] + bb[t + 256];
    out[(size_t)row * DD + t] = o0;
    out[(size_t)row * DD + t + 256] = o1;
    if (out2) {
        out2[(size_t)row * DD + t] = o0;
        out2[(size_t)row * DD + t + 256] = o1;
    }
    if (e2) {
        double sd = (double)o0 * o0 + (double)o1 * o1;
#pragma unroll
        for (int off = 32; off; off >>= 1) sd += __shfl_down(sd, off);
        if ((t & 63) == 0) dbuf[t >> 6] = sd;
        __syncthreads();
        if (t == 0) e2[row] = (dbuf[0] + dbuf[1]) + (dbuf[2] + dbuf[3]);
    }
}

// =======================================================================
// VQ (UNCHANGED from round 4)
// =======================================================================
__global__ __launch_bounds__(512) void vq_k(
    const float* __restrict__ z, const float* __restrict__ emb,
    const double* __restrict__ e2,
    float* __restrict__ zq, float* __restrict__ enc, float* __restrict__ idxo,
    double* __restrict__ lossp, int* __restrict__ counts)
{
    __shared__ float zs[32][68];   // [k][row]
    __shared__ float es[32][68];   // [k][code]
    __shared__ int   kms[64];
    __shared__ double dred[8];
    __shared__ int   cnt_s[64];

    const int bid = blockIdx.x;
    const int b   = bid >> 5;
    const int m0  = (bid & 31) * 64;
    const int tid = threadIdx.x;
    const int tx  = tid & 15, ty = tid >> 4;

    const float* zb = z   + ((size_t)b * TTOK + m0) * DD;
    const float* eb = emb + (size_t)b * NE * DD;

    double acc[2][4];
#pragma unroll
    for (int r = 0; r < 2; ++r)
#pragma unroll
        for (int j = 0; j < 4; ++j) acc[r][j] = 0.0;

    const int lrow = tid >> 3, lc4 = tid & 7;

    for (int kk = 0; kk < DD; kk += 32) {
        __syncthreads();
        {
            float4 t4 = *reinterpret_cast<const float4*>(&zb[(size_t)lrow * DD + kk + lc4 * 4]);
            zs[lc4 * 4 + 0][lrow] = t4.x;
            zs[lc4 * 4 + 1][lrow] = t4.y;
            zs[lc4 * 4 + 2][lrow] = t4.z;
            zs[lc4 * 4 + 3][lrow] = t4.w;
            float4 e4 = *reinterpret_cast<const float4*>(&eb[(size_t)lrow * DD + kk + lc4 * 4]);
            es[lc4 * 4 + 0][lrow] = e4.x;
            es[lc4 * 4 + 1][lrow] = e4.y;
            es[lc4 * 4 + 2][lrow] = e4.z;
            es[lc4 * 4 + 3][lrow] = e4.w;
        }
        __syncthreads();
#pragma unroll
        for (int k = 0; k < 32; ++k) {
            float2 zv = *reinterpret_cast<const float2*>(&zs[k][ty * 2]);
            float4 ev = *reinterpret_cast<const float4*>(&es[k][tx * 4]);
            double z0 = (double)zv.x, z1 = (double)zv.y;
            double e0 = (double)ev.x, e1 = (double)ev.y;
            double e2d = (double)ev.z, e3 = (double)ev.w;
            acc[0][0] = fma(z0, e0, acc[0][0]);
            acc[0][1] = fma(z0, e1, acc[0][1]);
            acc[0][2] = fma(z0, e2d, acc[0][2]);
            acc[0][3] = fma(z0, e3, acc[0][3]);
            acc[1][0] = fma(z1, e0, acc[1][0]);
            acc[1][1] = fma(z1, e1, acc[1][1]);
            acc[1][2] = fma(z1, e2d, acc[1][2]);
            acc[1][3] = fma(z1, e3, acc[1][3]);
        }
    }

    double e2v[4];
#pragma unroll
    for (int j = 0; j < 4; ++j) e2v[j] = e2[b * NE + tx * 4 + j];

    double vmin[2]; int imin[2];
#pragma unroll
    for (int r = 0; r < 2; ++r) {
        vmin[r] = e2v[0] - 2.0 * acc[r][0];
        imin[r] = tx * 4;
#pragma unroll
        for (int j = 1; j < 4; ++j) {
            double s = e2v[j] - 2.0 * acc[r][j];
            if (s < vmin[r]) { vmin[r] = s; imin[r] = tx * 4 + j; }
        }
    }
#pragma unroll
    for (int off = 1; off < 16; off <<= 1) {
#pragma unroll
        for (int r = 0; r < 2; ++r) {
            double ov = __shfl_xor(vmin[r], off);
            int    oi = __shfl_xor(imin[r], off);
            if (ov < vmin[r] || (ov == vmin[r] && oi < imin[r])) { vmin[r] = ov; imin[r] = oi; }
        }
    }
    if (tid < 64) cnt_s[tid] = 0;
    if (tx == 0) { kms[ty * 2] = imin[0]; kms[ty * 2 + 1] = imin[1]; }
    __syncthreads();
    if (tid < 64) atomicAdd(&cnt_s[kms[tid]], 1);

    const int row = tid >> 3, p = tid & 7;
    const int km  = kms[row];
    const float* zr = &zb[(size_t)row * DD];
    const float* er = &eb[(size_t)km * DD];
    const size_t grow = (size_t)b * TTOK + m0 + row;
    float* zqr = zq + grow * DD;
    double lsum = 0.0;
#pragma unroll 4
    for (int i = 0; i < 16; ++i) {
        int col = (i * 8 + p) * 4;
        float4 zv = *reinterpret_cast<const float4*>(&zr[col]);
        float4 ev = *reinterpret_cast<const float4*>(&er[col]);
        float d0 = ev.x - zv.x, d1 = ev.y - zv.y, d2 = ev.z - zv.z, d3 = ev.w - zv.w;
        lsum += (double)d0 * d0 + (double)d1 * d1 + (double)d2 * d2 + (double)d3 * d3;
        float4 o4 = {zv.x + d0, zv.y + d1, zv.z + d2, zv.w + d3};
        *reinterpret_cast<float4*>(&zqr[col]) = o4;
    }
    {
        float* ep = enc + grow * NE + p * 8;
        float4 o0, o1;
        o0.x = (p * 8 + 0 == km) ? 1.f : 0.f;
        o0.y = (p * 8 + 1 == km) ? 1.f : 0.f;
        o0.z = (p * 8 + 2 == km) ? 1.f : 0.f;
        o0.w = (p * 8 + 3 == km) ? 1.f : 0.f;
        o1.x = (p * 8 + 4 == km) ? 1.f : 0.f;
        o1.y = (p * 8 + 5 == km) ? 1.f : 0.f;
        o1.z = (p * 8 + 6 == km) ? 1.f : 0.f;
        o1.w = (p * 8 + 7 == km) ? 1.f : 0.f;
        *reinterpret_cast<float4*>(ep)     = o0;
        *reinterpret_cast<float4*>(ep + 4) = o1;
    }
    if (tid < 64) idxo[(size_t)b * TTOK + m0 + tid] = (float)kms[tid];

#pragma unroll
    for (int off = 32; off; off >>= 1) lsum += __shfl_down(lsum, off);
    if ((tid & 63) == 0) dred[tid >> 6] = lsum;
    __syncthreads();
    if (tid == 0) {
        double t = 0.0;
#pragma unroll
        for (int w = 0; w < 8; ++w) t += dred[w];
        lossp[bid] = t;
    }
    if (tid < 64 && cnt_s[tid]) atomicAdd(&counts[tid], cnt_s[tid]);
}

// =======================================================================
// Finalize (UNCHANGED)
// =======================================================================
__global__ void fin_k(const double* __restrict__ lossp, const int* __restrict__ counts,
                      float* __restrict__ loss_out, float* __restrict__ perp_out)
{
    int tid = threadIdx.x;  // 64 threads
    if (tid == 0) {
        double tot = 0.0;
        for (int i = 0; i < 512; ++i) tot += lossp[i];
        loss_out[0] = (float)(1.5 * tot / 16777216.0);   // (BETA+1)*mean
    }
    float e = counts[tid] / 32768.0f;
    float term = e * logf(e + 1e-10f);
#pragma unroll
    for (int off = 32; off; off >>= 1) term += __shfl_down(term, off);
    if (tid == 0) perp_out[0] = expf(-term);
}

// =======================================================================
extern "C" void kernel_launch(void* const* d_in, const int* in_sizes, int n_in,
                              void* d_out, int out_size, void* d_ws, size_t ws_size,
                              hipStream_t stream)
{
    (void)in_sizes; (void)n_in; (void)out_size; (void)ws_size;
    const float* x_enc = (const float*)d_in[0];
    const float* z     = (const float*)d_in[1];
    const float* tab   = (const float*)d_in[2];
    const float* wq1 = (const float*)d_in[3];  const float* bq1 = (const float*)d_in[4];
    const float* wk1 = (const float*)d_in[5];  const float* bk1 = (const float*)d_in[6];
    const float* wv1 = (const float*)d_in[7];  const float* bv1 = (const float*)d_in[8];
    const float* wo1 = (const float*)d_in[9];  const float* bo1 = (const float*)d_in[10];
    const float* wq2 = (const float*)d_in[11]; const float* bq2 = (const float*)d_in[12];
    const float* wk2 = (const float*)d_in[13]; const float* bk2 = (const float*)d_in[14];
    const float* wv2 = (const float*)d_in[15]; const float* bv2 = (const float*)d_in[16];
    const float* wo2 = (const float*)d_in[17]; const float* bo2 = (const float*)d_in[18];
    const float* ln2g = (const float*)d_in[19]; const float* ln2b = (const float*)d_in[20];
    const float* ln1g = (const float*)d_in[21]; const float* ln1b = (const float*)d_in[22];

    float* ws  = (float*)d_ws;
    float* out = (float*)d_out;

    float* k1   = ws + WS_K1;
    float* v1   = ws + WS_V1;
    float* emb0 = ws + WS_EMB0;
    float* q1   = ws + WS_Q1;
    float* att1 = ws + WS_ATT1;
    float* emb1 = ws + WS_EMB1;
    float* q2   = ws + WS_Q2;
    float* k2   = ws + WS_K2;
    float* v2   = ws + WS_V2;
    float* att2 = ws + WS_ATT2;
    float* ybuf = ws + WS_YBUF;
    float* embf = ws + WS_EMBF;
    double* e2    = (double*)(ws + WS_E2);
    double* lossp = (double*)(ws + WS_LOSSP);
    int*    cnts  = (int*)(ws + WS_CNT);

    hipMemsetAsync(cnts, 0, NE * sizeof(int), stream);

    pe_emb0_k<<<64, 256, 0, stream>>>(tab, emb0);

    gemm_q1_k<<<128, 256, 0, stream>>>(emb0, wq1, bq1, q1);
    gemm_kv_k<<<512, 256, 0, stream>>>(x_enc, wk1, bk1, k1,
                                       wv1, bv1, v1);
    attn_k<<<256, 128, 0, stream>>>(q1, 1, k1, v1, att1, SENC);

    gemm_bias_k<1><<<dim3(16, 8), 256, 0, stream>>>(att1, wo1, bo1, ybuf,
                                                    nullptr, nullptr, nullptr,
                                                    nullptr, nullptr, nullptr);
    ln_k<<<1024, 256, 0, stream>>>(emb0, 1, ybuf, ln1g, ln1b, emb1, nullptr, nullptr);

    gemm_bias_k<3><<<dim3(16, 8), 256, 0, stream>>>(emb1, wq2, bq2, q2,
                                                    wk2, bk2, k2,
                                                    wv2, bv2, v2);
    attn_k<<<256, 128, 0, stream>>>(q2, 0, k2, v2, att2, 64);

    gemm_bias_k<1><<<dim3(16, 8), 256, 0, stream>>>(att2, wo2, bo2, ybuf,
                                                    nullptr, nullptr, nullptr,
                                                    nullptr, nullptr, nullptr);
    ln_k<<<1024, 256, 0, stream>>>(emb1, 0, ybuf, ln2g, ln2b, embf, out + OUT_EMB, e2);

    vq_k<<<512, 512, 0, stream>>>(z, embf, e2,
                                  out + OUT_ZQ, out + OUT_ENC, out + OUT_IDX,
                                  lossp, cnts);
    fin_k<<<1, 64, 0, stream>>>(lossp, cnts, out + OUT_LOSS, out + OUT_PERP);
}

// Round 12
// 605.266 us; speedup vs baseline: 1.3918x; 1.3918x over previous
//
#include <hip/hip_runtime.h>
#include <math.h>

#define DD     512
#define NBATCH 16
#define SENC   1024
#define TTOK   2048
#define NHEAD  8
#define HDIM   64
#define NE     64

// ---------------- workspace layout (float element offsets) ----------------
#define WS_K1    0                           // 16*1024*512
#define WS_V1    (WS_K1 + NBATCH*SENC*DD)
#define WS_EMB0  (WS_V1 + NBATCH*SENC*DD)    // 64*512
#define WS_Q1    (WS_EMB0 + NE*DD)
#define WS_ATT1  (WS_Q1 + NE*DD)             // 16*64*512
#define WS_EMB1  (WS_ATT1 + NBATCH*NE*DD)
#define WS_Q2    (WS_EMB1 + NBATCH*NE*DD)
#define WS_K2    (WS_Q2 + NBATCH*NE*DD)
#define WS_V2    (WS_K2 + NBATCH*NE*DD)
#define WS_ATT2  (WS_V2 + NBATCH*NE*DD)
#define WS_YBUF  (WS_ATT2 + NBATCH*NE*DD)
#define WS_EMBF  (WS_YBUF + NBATCH*NE*DD)
#define WS_E2    (WS_EMBF + NBATCH*NE*DD)    // doubles: 16*64  (=2048 floats)
#define WS_LOSSP (WS_E2 + 2*NBATCH*NE)       // doubles: 512    (=1024 floats)
#define WS_CNT   (WS_LOSSP + 2*512)          // ints: 64

// ---------------- output layout (float element offsets) ----------------
#define OUT_ZQ   0
#define OUT_LOSS (NBATCH*TTOK*DD)            // 16777216
#define OUT_PERP (OUT_LOSS + 1)
#define OUT_ENC  (OUT_PERP + 1)
#define OUT_IDX  (OUT_ENC + NBATCH*TTOK*NE)
#define OUT_EMB  (OUT_IDX + NBATCH*TTOK)

// =======================================================================
// PE + emb0  (UNCHANGED — stage A must stay bit-identical)
// =======================================================================
__global__ __launch_bounds__(256) void pe_emb0_k(const float* __restrict__ tab,
                                                 float* __restrict__ emb0)
{
    int p = blockIdx.x;
    for (int c = threadIdx.x; c < DD; c += 256) {
        int ie = c & ~1;
        float denom = (float)pow(10000.0, (double)ie / 512.0);
        float ang = (float)p / denom;            // f32 division, matches np
        double v = (c & 1) ? cos((double)ang) : sin((double)ang);
        emb0[p * DD + c] = tab[p * DD + c] + (float)v;
    }
}

// =======================================================================
// q1 projection (kept from round 11 — 128 blocks, coalesced, bit-identical)
// =======================================================================
__global__ __launch_bounds__(256) void gemm_q1_k(
    const float* __restrict__ A, const float* __restrict__ W,
    const float* __restrict__ B, float* __restrict__ C)
{
    const int rg   = blockIdx.x >> 3;          // 16 row-groups of 4
    const int c0   = (blockIdx.x & 7) * 64;
    const int ri   = threadIdx.x >> 6;         // 0..3
    const int lane = threadIdx.x & 63;
    const int row  = rg * 4 + ri;
    const float* Ar = A + (size_t)row * DD;
    const float* Wc = W + c0 + lane;
    float acc = 0.f;
#pragma unroll 8
    for (int k = 0; k < DD; ++k)
        acc = fmaf(Ar[k], Wc[(size_t)k * DD], acc);
    C[(size_t)row * DD + c0 + lane] = acc + B[c0 + lane];
}

// =======================================================================
// Big-M GEMM (K/V projection) — UNCHANGED (measured 218 us best-of-4).
// =======================================================================
__global__ __launch_bounds__(256) void gemm_kv_k(
    const float* __restrict__ A,
    const float* __restrict__ W0, const float* __restrict__ B0, float* __restrict__ C0,
    const float* __restrict__ W1, const float* __restrict__ B1, float* __restrict__ C1)
{
    __shared__ float As[32][260];       // [k][m] 256 rows + pad
    __shared__ float Ws[2][32][68];     // [k][n]
    const int bid = blockIdx.x;
    const int xcd = bid & 7;
    const int idx = bid >> 3;
    const int m0 = (xcd * 8 + (idx >> 3)) * 256;
    const int n0 = (idx & 7) * 64;
    const int tid = threadIdx.x;
    const int tx = tid & 15, ty = tid >> 4;   // tx: 4 n-cols, ty: 16 m-rows

    float acc[2][16][4];
#pragma unroll
    for (int o = 0; o < 2; ++o)
#pragma unroll
        for (int i = 0; i < 16; ++i)
#pragma unroll
            for (int j = 0; j < 4; ++j) acc[o][i][j] = 0.f;

    for (int kk = 0; kk < DD; kk += 32) {
        __syncthreads();
#pragma unroll
        for (int l = 0; l < 8; ++l) {             // A: 2048 float4
            int fid = l * 256 + tid;
            int row = fid >> 3, c4 = fid & 7;
            float4 v = *reinterpret_cast<const float4*>(&A[(size_t)(m0 + row) * DD + kk + c4 * 4]);
            As[c4 * 4 + 0][row] = v.x;
            As[c4 * 4 + 1][row] = v.y;
            As[c4 * 4 + 2][row] = v.z;
            As[c4 * 4 + 3][row] = v.w;
        }
        {
            int kr = tid >> 4, c4 = tid & 15;     // W: 512 float4 per output
            *reinterpret_cast<float4*>(&Ws[0][kr][c4 * 4]) =
                *reinterpret_cast<const float4*>(&W0[(size_t)(kk + kr) * DD + n0 + c4 * 4]);
            *reinterpret_cast<float4*>(&Ws[0][kr + 16][c4 * 4]) =
                *reinterpret_cast<const float4*>(&W0[(size_t)(kk + kr + 16) * DD + n0 + c4 * 4]);
            *reinterpret_cast<float4*>(&Ws[1][kr][c4 * 4]) =
                *reinterpret_cast<const float4*>(&W1[(size_t)(kk + kr) * DD + n0 + c4 * 4]);
            *reinterpret_cast<float4*>(&Ws[1][kr + 16][c4 * 4]) =
                *reinterpret_cast<const float4*>(&W1[(size_t)(kk + kr + 16) * DD + n0 + c4 * 4]);
        }
        __syncthreads();
#pragma unroll 4
        for (int k = 0; k < 32; ++k) {
            float4 a0 = *reinterpret_cast<const float4*>(&As[k][ty * 16]);
            float4 a1 = *reinterpret_cast<const float4*>(&As[k][ty * 16 + 4]);
            float4 a2 = *reinterpret_cast<const float4*>(&As[k][ty * 16 + 8]);
            float4 a3 = *reinterpret_cast<const float4*>(&As[k][ty * 16 + 12]);
            float a[16] = {a0.x, a0.y, a0.z, a0.w, a1.x, a1.y, a1.z, a1.w,
                           a2.x, a2.y, a2.z, a2.w, a3.x, a3.y, a3.z, a3.w};
            float4 w0 = *reinterpret_cast<const float4*>(&Ws[0][k][tx * 4]);
            float4 w1 = *reinterpret_cast<const float4*>(&Ws[1][k][tx * 4]);
#pragma unroll
            for (int i = 0; i < 16; ++i) {
                acc[0][i][0] = fmaf(a[i], w0.x, acc[0][i][0]);
                acc[0][i][1] = fmaf(a[i], w0.y, acc[0][i][1]);
                acc[0][i][2] = fmaf(a[i], w0.z, acc[0][i][2]);
                acc[0][i][3] = fmaf(a[i], w0.w, acc[0][i][3]);
                acc[1][i][0] = fmaf(a[i], w1.x, acc[1][i][0]);
                acc[1][i][1] = fmaf(a[i], w1.y, acc[1][i][1]);
                acc[1][i][2] = fmaf(a[i], w1.z, acc[1][i][2]);
                acc[1][i][3] = fmaf(a[i], w1.w, acc[1][i][3]);
            }
        }
    }
    float* Cp[2] = {C0, C1};
    const float* Bp[2] = {B0, B1};
#pragma unroll
    for (int o = 0; o < 2; ++o) {
        float4 bv = *reinterpret_cast<const float4*>(&Bp[o][n0 + tx * 4]);
#pragma unroll
        for (int i = 0; i < 16; ++i) {
            int row = m0 + ty * 16 + i;
            float4 o4 = {acc[o][i][0] + bv.x, acc[o][i][1] + bv.y,
                         acc[o][i][2] + bv.z, acc[o][i][3] + bv.w};
            *reinterpret_cast<float4*>(&Cp[o][(size_t)row * DD + n0 + tx * 4]) = o4;
        }
    }
}

// =======================================================================
// Generic f32 GEMM + bias (UNCHANGED — used for small-M GEMMs)
// =======================================================================
template <int NOUT>
__global__ __launch_bounds__(256) void gemm_bias_k(
    const float* __restrict__ A,
    const float* __restrict__ W0, const float* __restrict__ B0, float* __restrict__ C0,
    const float* __restrict__ W1, const float* __restrict__ B1, float* __restrict__ C1,
    const float* __restrict__ W2, const float* __restrict__ B2, float* __restrict__ C2)
{
    __shared__ float As[32][64];          // [k][m]
    __shared__ float Ws[NOUT][32][64];    // [k][n]
    const int m0 = blockIdx.x * 64;
    const int n0 = blockIdx.y * 64;
    const int tid = threadIdx.x;
    const int tx = tid & 15, ty = tid >> 4;

    float acc[NOUT][4][4];
#pragma unroll
    for (int o = 0; o < NOUT; ++o)
#pragma unroll
        for (int i = 0; i < 4; ++i)
#pragma unroll
            for (int j = 0; j < 4; ++j) acc[o][i][j] = 0.f;

    const float* Wp[3] = {W0, W1, W2};

    for (int kk = 0; kk < DD; kk += 32) {
        __syncthreads();
#pragma unroll
        for (int l = 0; l < 2; ++l) {
            int fid = l * 256 + tid;          // 512 float4 of A tile
            int row = fid >> 3, c4 = fid & 7;
            float4 v = *reinterpret_cast<const float4*>(&A[(size_t)(m0 + row) * DD + kk + c4 * 4]);
            As[c4 * 4 + 0][row] = v.x;
            As[c4 * 4 + 1][row] = v.y;
            As[c4 * 4 + 2][row] = v.z;
            As[c4 * 4 + 3][row] = v.w;
        }
#pragma unroll
        for (int o = 0; o < NOUT; ++o) {
#pragma unroll
            for (int l = 0; l < 2; ++l) {
                int fid = l * 256 + tid;      // 512 float4 of W tile
                int kr = fid >> 4, c4 = fid & 15;
                *reinterpret_cast<float4*>(&Ws[o][kr][c4 * 4]) =
                    *reinterpret_cast<const float4*>(&Wp[o][(size_t)(kk + kr) * DD + n0 + c4 * 4]);
            }
        }
        __syncthreads();
#pragma unroll
        for (int k = 0; k < 32; ++k) {
            float4 av = *reinterpret_cast<const float4*>(&As[k][ty * 4]);
            float a[4] = {av.x, av.y, av.z, av.w};
#pragma unroll
            for (int o = 0; o < NOUT; ++o) {
                float4 wv = *reinterpret_cast<const float4*>(&Ws[o][k][tx * 4]);
#pragma unroll
                for (int i = 0; i < 4; ++i) {
                    acc[o][i][0] = fmaf(a[i], wv.x, acc[o][i][0]);
                    acc[o][i][1] = fmaf(a[i], wv.y, acc[o][i][1]);
                    acc[o][i][2] = fmaf(a[i], wv.z, acc[o][i][2]);
                    acc[o][i][3] = fmaf(a[i], wv.w, acc[o][i][3]);
                }
            }
        }
    }
    float* Cp[3] = {C0, C1, C2};
    const float* Bp[3] = {B0, B1, B2};
#pragma unroll
    for (int o = 0; o < NOUT; ++o) {
#pragma unroll
        for (int i = 0; i < 4; ++i) {
            int row = m0 + ty * 4 + i;
#pragma unroll
            for (int j = 0; j < 4; ++j) {
                int col = n0 + tx * 4 + j;
                Cp[o][(size_t)row * DD + col] = acc[o][i][j] + Bp[o][col];
            }
        }
    }
}

// =======================================================================
// MHA core, round 12: K+V back in LDS (round-10 form, measured) + T14
// async-STAGE: next tile's 16 staging float4s are loaded into REGISTERS
// before the current tile's compute phase (2048 FMAs of cover), written
// to LDS after the post-compute barrier. Pure data-movement reordering:
// same LDS layout, same values, same fmaf order -> bit-identical.
// =======================================================================
__global__ __launch_bounds__(128) void attn_k(
    const float* __restrict__ q, int q_shared,
    const float* __restrict__ kmat, const float* __restrict__ vmat,
    float* __restrict__ outp, int slen)
{
    __shared__ float qs[32][68];
    __shared__ float kst[64][68]; // [e][j] (transposed)
    __shared__ float vs[64][68];  // [j][c]
    int bid = blockIdx.x;
    int b = bid >> 4, h = (bid >> 1) & 7, half = bid & 1;
    int tid = threadIdx.x;
    const float* qb = q + (q_shared ? (size_t)0 : (size_t)b * 64 * DD);
    const float* kb = kmat + (size_t)b * slen * DD;
    const float* vb = vmat + (size_t)b * slen * DD;

#pragma unroll
    for (int l = 0; l < 4; ++l) {               // 32 rows x 16 float4
        int fid = l * 128 + tid;
        int r = fid >> 4, c4 = fid & 15;
        *reinterpret_cast<float4*>(&qs[r][c4 * 4]) =
            *reinterpret_cast<const float4*>(&qb[(size_t)(half * 32 + r) * DD + h * HDIM + c4 * 4]);
    }
    const int row = tid >> 2, c4 = tid & 3;     // row 0..31
    const int sr = tid >> 4, scc = tid & 15;    // staging: row-group, col4
    float acc[16];
#pragma unroll
    for (int i = 0; i < 16; ++i) acc[i] = 0.f;
    float m_run = -INFINITY, l_run = 0.f;

    float4 rk[8], rv[8];                        // prefetch registers

#define AKLOADS(S0)                                                                 \
    _Pragma("unroll")                                                               \
    for (int l = 0; l < 8; ++l) {                                                   \
        int r = l * 8 + sr;                                                         \
        rk[l] = *reinterpret_cast<const float4*>(&kb[(size_t)((S0) + r) * DD + h * HDIM + scc * 4]); \
        rv[l] = *reinterpret_cast<const float4*>(&vb[(size_t)((S0) + r) * DD + h * HDIM + scc * 4]); \
    }

#define AKSTORES()                                                                  \
    _Pragma("unroll")                                                               \
    for (int l = 0; l < 8; ++l) {                                                   \
        int r = l * 8 + sr;                                                         \
        kst[scc * 4 + 0][r] = rk[l].x;                                              \
        kst[scc * 4 + 1][r] = rk[l].y;                                              \
        kst[scc * 4 + 2][r] = rk[l].z;                                              \
        kst[scc * 4 + 3][r] = rk[l].w;                                              \
        *reinterpret_cast<float4*>(&vs[r][scc * 4]) = rv[l];                        \
    }

    // prologue: stage tile 0
    AKLOADS(0)
    AKSTORES()
    __syncthreads();

    const int ntile = slen >> 6;
    for (int t = 0; t < ntile; ++t) {
        if (t + 1 < ntile) { AKLOADS((t + 1) * 64) }   // issue early

        float p[16];
#pragma unroll
        for (int i = 0; i < 16; ++i) p[i] = 0.f;
#pragma unroll 4
        for (int e = 0; e < 64; ++e) {
            float qv = qs[row][e];
#pragma unroll
            for (int j4 = 0; j4 < 4; ++j4) {
                float4 k4 = *reinterpret_cast<const float4*>(&kst[e][c4 * 16 + j4 * 4]);
                p[j4 * 4 + 0] = fmaf(qv, k4.x, p[j4 * 4 + 0]);
                p[j4 * 4 + 1] = fmaf(qv, k4.y, p[j4 * 4 + 1]);
                p[j4 * 4 + 2] = fmaf(qv, k4.z, p[j4 * 4 + 2]);
                p[j4 * 4 + 3] = fmaf(qv, k4.w, p[j4 * 4 + 3]);
            }
        }
#pragma unroll
        for (int i = 0; i < 16; ++i) p[i] *= 0.125f;   // / sqrt(64), exact
        float mx = p[0];
#pragma unroll
        for (int i = 1; i < 16; ++i) mx = fmaxf(mx, p[i]);
        mx = fmaxf(mx, __shfl_xor(mx, 1));
        mx = fmaxf(mx, __shfl_xor(mx, 2));
        float m_new = fmaxf(m_run, mx);
        float scale = expf(m_run - m_new);             // 0 on first tile
        float lsum = 0.f;
#pragma unroll
        for (int i = 0; i < 16; ++i) { p[i] = expf(p[i] - m_new); lsum += p[i]; }
        lsum += __shfl_xor(lsum, 1);
        lsum += __shfl_xor(lsum, 2);
        l_run = l_run * scale + lsum;
        m_run = m_new;
#pragma unroll
        for (int i = 0; i < 16; ++i) acc[i] *= scale;

#pragma unroll 16
        for (int j = 0; j < 64; ++j) {
            float pv = __shfl(p[j & 15], j >> 4, 4);   // owner lane in quad
#pragma unroll
            for (int u = 0; u < 4; ++u) {
                float4 v4 = *reinterpret_cast<const float4*>(&vs[j][c4 * 16 + u * 4]);
                acc[u * 4 + 0] = fmaf(pv, v4.x, acc[u * 4 + 0]);
                acc[u * 4 + 1] = fmaf(pv, v4.y, acc[u * 4 + 1]);
                acc[u * 4 + 2] = fmaf(pv, v4.z, acc[u * 4 + 2]);
                acc[u * 4 + 3] = fmaf(pv, v4.w, acc[u * 4 + 3]);
            }
        }
        __syncthreads();                               // all reads of tile t done
        if (t + 1 < ntile) {
            AKSTORES()                                 // write tile t+1
            __syncthreads();
        }
    }
#undef AKLOADS
#undef AKSTORES

#pragma unroll
    for (int i = 0; i < 16; ++i) acc[i] /= l_run;
#pragma unroll
    for (int u = 0; u < 4; ++u) {
        float4 o4 = {acc[u * 4 + 0], acc[u * 4 + 1], acc[u * 4 + 2], acc[u * 4 + 3]};
        *reinterpret_cast<float4*>(&outp[((size_t)b * 64 + half * 32 + row) * DD + h * HDIM + c4 * 16 + u * 4]) = o4;
    }
}

// =======================================================================
// LayerNorm (UNCHANGED)
// =======================================================================
__device__ __forceinline__ float block_sum256(float v, float* sb)
{
#pragma unroll
    for (int off = 32; off; off >>= 1) v += __shfl_down(v, off);
    __syncthreads();
    if ((threadIdx.x & 63) == 0) sb[threadIdx.x >> 6] = v;
    __syncthreads();
    return (sb[0] + sb[1]) + (sb[2] + sb[3]);
}

__global__ __launch_bounds__(256) void ln_k(
    const float* __restrict__ res, int res_shared, const float* __restrict__ y,
    const float* __restrict__ g, const float* __restrict__ bb,
    float* __restrict__ out, float* __restrict__ out2, double* __restrict__ e2)
{
    __shared__ float sbuf[4];
    __shared__ double dbuf[4];
    int row = blockIdx.x;
    int t = threadIdx.x;
    const float* rp = res + (size_t)(res_shared ? (row & 63) : row) * DD;
    const float* yp = y + (size_t)row * DD;
    float x0 = rp[t] + yp[t];
    float x1 = rp[t + 256] + yp[t + 256];
    float m = block_sum256(x0 + x1, sbuf) / 512.0f;
    float d0 = x0 - m, d1 = x1 - m;
    float v = block_sum256(d0 * d0 + d1 * d1, sbuf) / 512.0f;
    float s = sqrtf(v + 1e-5f);
    float o0 = d0 / s * g[t] + bb[t];
    float o1 = d1 / s * g[t + 256] + bb[t + 256];
    out[(size_t)row * DD + t] = o0;
    out[(size_t)row * DD + t + 256] = o1;
    if (out2) {
        out2[(size_t)row * DD + t] = o0;
        out2[(size_t)row * DD + t + 256] = o1;
    }
    if (e2) {
        double sd = (double)o0 * o0 + (double)o1 * o1;
#pragma unroll
        for (int off = 32; off; off >>= 1) sd += __shfl_down(sd, off);
        if ((t & 63) == 0) dbuf[t >> 6] = sd;
        __syncthreads();
        if (t == 0) e2[row] = (dbuf[0] + dbuf[1]) + (dbuf[2] + dbuf[3]);
    }
}

// =======================================================================
// VQ (UNCHANGED from round 4)
// =======================================================================
__global__ __launch_bounds__(512) void vq_k(
    const float* __restrict__ z, const float* __restrict__ emb,
    const double* __restrict__ e2,
    float* __restrict__ zq, float* __restrict__ enc, float* __restrict__ idxo,
    double* __restrict__ lossp, int* __restrict__ counts)
{
    __shared__ float zs[32][68];   // [k][row]
    __shared__ float es[32][68];   // [k][code]
    __shared__ int   kms[64];
    __shared__ double dred[8];
    __shared__ int   cnt_s[64];

    const int bid = blockIdx.x;
    const int b   = bid >> 5;
    const int m0  = (bid & 31) * 64;
    const int tid = threadIdx.x;
    const int tx  = tid & 15, ty = tid >> 4;

    const float* zb = z   + ((size_t)b * TTOK + m0) * DD;
    const float* eb = emb + (size_t)b * NE * DD;

    double acc[2][4];
#pragma unroll
    for (int r = 0; r < 2; ++r)
#pragma unroll
        for (int j = 0; j < 4; ++j) acc[r][j] = 0.0;

    const int lrow = tid >> 3, lc4 = tid & 7;

    for (int kk = 0; kk < DD; kk += 32) {
        __syncthreads();
        {
            float4 t4 = *reinterpret_cast<const float4*>(&zb[(size_t)lrow * DD + kk + lc4 * 4]);
            zs[lc4 * 4 + 0][lrow] = t4.x;
            zs[lc4 * 4 + 1][lrow] = t4.y;
            zs[lc4 * 4 + 2][lrow] = t4.z;
            zs[lc4 * 4 + 3][lrow] = t4.w;
            float4 e4 = *reinterpret_cast<const float4*>(&eb[(size_t)lrow * DD + kk + lc4 * 4]);
            es[lc4 * 4 + 0][lrow] = e4.x;
            es[lc4 * 4 + 1][lrow] = e4.y;
            es[lc4 * 4 + 2][lrow] = e4.z;
            es[lc4 * 4 + 3][lrow] = e4.w;
        }
        __syncthreads();
#pragma unroll
        for (int k = 0; k < 32; ++k) {
            float2 zv = *reinterpret_cast<const float2*>(&zs[k][ty * 2]);
            float4 ev = *reinterpret_cast<const float4*>(&es[k][tx * 4]);
            double z0 = (double)zv.x, z1 = (double)zv.y;
            double e0 = (double)ev.x, e1 = (double)ev.y;
            double e2d = (double)ev.z, e3 = (double)ev.w;
            acc[0][0] = fma(z0, e0, acc[0][0]);
            acc[0][1] = fma(z0, e1, acc[0][1]);
            acc[0][2] = fma(z0, e2d, acc[0][2]);
            acc[0][3] = fma(z0, e3, acc[0][3]);
            acc[1][0] = fma(z1, e0, acc[1][0]);
            acc[1][1] = fma(z1, e1, acc[1][1]);
            acc[1][2] = fma(z1, e2d, acc[1][2]);
            acc[1][3] = fma(z1, e3, acc[1][3]);
        }
    }

    double e2v[4];
#pragma unroll
    for (int j = 0; j < 4; ++j) e2v[j] = e2[b * NE + tx * 4 + j];

    double vmin[2]; int imin[2];
#pragma unroll
    for (int r = 0; r < 2; ++r) {
        vmin[r] = e2v[0] - 2.0 * acc[r][0];
        imin[r] = tx * 4;
#pragma unroll
        for (int j = 1; j < 4; ++j) {
            double s = e2v[j] - 2.0 * acc[r][j];
            if (s < vmin[r]) { vmin[r] = s; imin[r] = tx * 4 + j; }
        }
    }
#pragma unroll
    for (int off = 1; off < 16; off <<= 1) {
#pragma unroll
        for (int r = 0; r < 2; ++r) {
            double ov = __shfl_xor(vmin[r], off);
            int    oi = __shfl_xor(imin[r], off);
            if (ov < vmin[r] || (ov == vmin[r] && oi < imin[r])) { vmin[r] = ov; imin[r] = oi; }
        }
    }
    if (tid < 64) cnt_s[tid] = 0;
    if (tx == 0) { kms[ty * 2] = imin[0]; kms[ty * 2 + 1] = imin[1]; }
    __syncthreads();
    if (tid < 64) atomicAdd(&cnt_s[kms[tid]], 1);

    const int row = tid >> 3, p = tid & 7;
    const int km  = kms[row];
    const float* zr = &zb[(size_t)row * DD];
    const float* er = &eb[(size_t)km * DD];
    const size_t grow = (size_t)b * TTOK + m0 + row;
    float* zqr = zq + grow * DD;
    double lsum = 0.0;
#pragma unroll 4
    for (int i = 0; i < 16; ++i) {
        int col = (i * 8 + p) * 4;
        float4 zv = *reinterpret_cast<const float4*>(&zr[col]);
        float4 ev = *reinterpret_cast<const float4*>(&er[col]);
        float d0 = ev.x - zv.x, d1 = ev.y - zv.y, d2 = ev.z - zv.z, d3 = ev.w - zv.w;
        lsum += (double)d0 * d0 + (double)d1 * d1 + (double)d2 * d2 + (double)d3 * d3;
        float4 o4 = {zv.x + d0, zv.y + d1, zv.z + d2, zv.w + d3};
        *reinterpret_cast<float4*>(&zqr[col]) = o4;
    }
    {
        float* ep = enc + grow * NE + p * 8;
        float4 o0, o1;
        o0.x = (p * 8 + 0 == km) ? 1.f : 0.f;
        o0.y = (p * 8 + 1 == km) ? 1.f : 0.f;
        o0.z = (p * 8 + 2 == km) ? 1.f : 0.f;
        o0.w = (p * 8 + 3 == km) ? 1.f : 0.f;
        o1.x = (p * 8 + 4 == km) ? 1.f : 0.f;
        o1.y = (p * 8 + 5 == km) ? 1.f : 0.f;
        o1.z = (p * 8 + 6 == km) ? 1.f : 0.f;
        o1.w = (p * 8 + 7 == km) ? 1.f : 0.f;
        *reinterpret_cast<float4*>(ep)     = o0;
        *reinterpret_cast<float4*>(ep + 4) = o1;
    }
    if (tid < 64) idxo[(size_t)b * TTOK + m0 + tid] = (float)kms[tid];

#pragma unroll
    for (int off = 32; off; off >>= 1) lsum += __shfl_down(lsum, off);
    if ((tid & 63) == 0) dred[tid >> 6] = lsum;
    __syncthreads();
    if (tid == 0) {
        double t = 0.0;
#pragma unroll
        for (int w = 0; w < 8; ++w) t += dred[w];
        lossp[bid] = t;
    }
    if (tid < 64 && cnt_s[tid]) atomicAdd(&counts[tid], cnt_s[tid]);
}

// =======================================================================
// Finalize (UNCHANGED)
// =======================================================================
__global__ void fin_k(const double* __restrict__ lossp, const int* __restrict__ counts,
                      float* __restrict__ loss_out, float* __restrict__ perp_out)
{
    int tid = threadIdx.x;  // 64 threads
    if (tid == 0) {
        double tot = 0.0;
        for (int i = 0; i < 512; ++i) tot += lossp[i];
        loss_out[0] = (float)(1.5 * tot / 16777216.0);   // (BETA+1)*mean
    }
    float e = counts[tid] / 32768.0f;
    float term = e * logf(e + 1e-10f);
#pragma unroll
    for (int off = 32; off; off >>= 1) term += __shfl_down(term, off);
    if (tid == 0) perp_out[0] = expf(-term);
}

// =======================================================================
extern "C" void kernel_launch(void* const* d_in, const int* in_sizes, int n_in,
                              void* d_out, int out_size, void* d_ws, size_t ws_size,
                              hipStream_t stream)
{
    (void)in_sizes; (void)n_in; (void)out_size; (void)ws_size;
    const float* x_enc = (const float*)d_in[0];
    const float* z     = (const float*)d_in[1];
    const float* tab   = (const float*)d_in[2];
    const float* wq1 = (const float*)d_in[3];  const float* bq1 = (const float*)d_in[4];
    const float* wk1 = (const float*)d_in[5];  const float* bk1 = (const float*)d_in[6];
    const float* wv1 = (const float*)d_in[7];  const float* bv1 = (const float*)d_in[8];
    const float* wo1 = (const float*)d_in[9];  const float* bo1 = (const float*)d_in[10];
    const float* wq2 = (const float*)d_in[11]; const float* bq2 = (const float*)d_in[12];
    const float* wk2 = (const float*)d_in[13]; const float* bk2 = (const float*)d_in[14];
    const float* wv2 = (const float*)d_in[15]; const float* bv2 = (const float*)d_in[16];
    const float* wo2 = (const float*)d_in[17]; const float* bo2 = (const float*)d_in[18];
    const float* ln2g = (const float*)d_in[19]; const float* ln2b = (const float*)d_in[20];
    const float* ln1g = (const float*)d_in[21]; const float* ln1b = (const float*)d_in[22];

    float* ws  = (float*)d_ws;
    float* out = (float*)d_out;

    float* k1   = ws + WS_K1;
    float* v1   = ws + WS_V1;
    float* emb0 = ws + WS_EMB0;
    float* q1   = ws + WS_Q1;
    float* att1 = ws + WS_ATT1;
    float* emb1 = ws + WS_EMB1;
    float* q2   = ws + WS_Q2;
    float* k2   = ws + WS_K2;
    float* v2   = ws + WS_V2;
    float* att2 = ws + WS_ATT2;
    float* ybuf = ws + WS_YBUF;
    float* embf = ws + WS_EMBF;
    double* e2    = (double*)(ws + WS_E2);
    double* lossp = (double*)(ws + WS_LOSSP);
    int*    cnts  = (int*)(ws + WS_CNT);

    hipMemsetAsync(cnts, 0, NE * sizeof(int), stream);

    pe_emb0_k<<<64, 256, 0, stream>>>(tab, emb0);

    gemm_q1_k<<<128, 256, 0, stream>>>(emb0, wq1, bq1, q1);
    gemm_kv_k<<<512, 256, 0, stream>>>(x_enc, wk1, bk1, k1,
                                       wv1, bv1, v1);
    attn_k<<<256, 128, 0, stream>>>(q1, 1, k1, v1, att1, SENC);

    gemm_bias_k<1><<<dim3(16, 8), 256, 0, stream>>>(att1, wo1, bo1, ybuf,
                                                    nullptr, nullptr, nullptr,
                                                    nullptr, nullptr, nullptr);
    ln_k<<<1024, 256, 0, stream>>>(emb0, 1, ybuf, ln1g, ln1b, emb1, nullptr, nullptr);

    gemm_bias_k<3><<<dim3(16, 8), 256, 0, stream>>>(emb1, wq2, bq2, q2,
                                                    wk2, bk2, k2,
                                                    wv2, bv2, v2);
    attn_k<<<256, 128, 0, stream>>>(q2, 0, k2, v2, att2, 64);

    gemm_bias_k<1><<<dim3(16, 8), 256, 0, stream>>>(att2, wo2, bo2, ybuf,
                                                    nullptr, nullptr, nullptr,
                                                    nullptr, nullptr, nullptr);
    ln_k<<<1024, 256, 0, stream>>>(emb1, 0, ybuf, ln2g, ln2b, embf, out + OUT_EMB, e2);

    vq_k<<<512, 512, 0, stream>>>(z, embf, e2,
                                  out + OUT_ZQ, out + OUT_ENC, out + OUT_IDX,
                                  lossp, cnts);
    fin_k<<<1, 64, 0, stream>>>(lossp, cnts, out + OUT_LOSS, out + OUT_PERP);
}

// Round 13
// 574.718 us; speedup vs baseline: 1.4658x; 1.0532x over previous
//
#include <hip/hip_runtime.h>
#include <math.h>

#define DD     512
#define NBATCH 16
#define SENC   1024
#define TTOK   2048
#define NHEAD  8
#define HDIM   64
#define NE     64

// ---------------- workspace layout (float element offsets) ----------------
#define WS_K1    0                           // 16*1024*512
#define WS_V1    (WS_K1 + NBATCH*SENC*DD)
#define WS_EMB0  (WS_V1 + NBATCH*SENC*DD)    // 64*512
#define WS_Q1    (WS_EMB0 + NE*DD)
#define WS_ATT1  (WS_Q1 + NE*DD)             // 16*64*512
#define WS_EMB1  (WS_ATT1 + NBATCH*NE*DD)
#define WS_Q2    (WS_EMB1 + NBATCH*NE*DD)
#define WS_K2    (WS_Q2 + NBATCH*NE*DD)
#define WS_V2    (WS_K2 + NBATCH*NE*DD)
#define WS_ATT2  (WS_V2 + NBATCH*NE*DD)
#define WS_YBUF  (WS_ATT2 + NBATCH*NE*DD)
#define WS_EMBF  (WS_YBUF + NBATCH*NE*DD)
#define WS_E2    (WS_EMBF + NBATCH*NE*DD)    // doubles: 16*64  (=2048 floats)
#define WS_LOSSP (WS_E2 + 2*NBATCH*NE)       // doubles: 512    (=1024 floats)
#define WS_CNT   (WS_LOSSP + 2*512)          // ints: 64

// ---------------- output layout (float element offsets) ----------------
#define OUT_ZQ   0
#define OUT_LOSS (NBATCH*TTOK*DD)            // 16777216
#define OUT_PERP (OUT_LOSS + 1)
#define OUT_ENC  (OUT_PERP + 1)
#define OUT_IDX  (OUT_ENC + NBATCH*TTOK*NE)
#define OUT_EMB  (OUT_IDX + NBATCH*TTOK)

// =======================================================================
// PE + emb0  (UNCHANGED — stage A must stay bit-identical)
// =======================================================================
__global__ __launch_bounds__(256) void pe_emb0_k(const float* __restrict__ tab,
                                                 float* __restrict__ emb0)
{
    int p = blockIdx.x;
    for (int c = threadIdx.x; c < DD; c += 256) {
        int ie = c & ~1;
        float denom = (float)pow(10000.0, (double)ie / 512.0);
        float ang = (float)p / denom;            // f32 division, matches np
        double v = (c & 1) ? cos((double)ang) : sin((double)ang);
        emb0[p * DD + c] = tab[p * DD + c] + (float)v;
    }
}

// =======================================================================
// q1 projection (kept — 128 blocks, coalesced, bit-identical)
// =======================================================================
__global__ __launch_bounds__(256) void gemm_q1_k(
    const float* __restrict__ A, const float* __restrict__ W,
    const float* __restrict__ B, float* __restrict__ C)
{
    const int rg   = blockIdx.x >> 3;          // 16 row-groups of 4
    const int c0   = (blockIdx.x & 7) * 64;
    const int ri   = threadIdx.x >> 6;         // 0..3
    const int lane = threadIdx.x & 63;
    const int row  = rg * 4 + ri;
    const float* Ar = A + (size_t)row * DD;
    const float* Wc = W + c0 + lane;
    float acc = 0.f;
#pragma unroll 8
    for (int k = 0; k < DD; ++k)
        acc = fmaf(Ar[k], Wc[(size_t)k * DD], acc);
    C[(size_t)row * DD + c0 + lane] = acc + B[c0 + lane];
}

// =======================================================================
// Big-M GEMM (K/V projection) — UNCHANGED (measured 218 us best-of-4).
// =======================================================================
__global__ __launch_bounds__(256) void gemm_kv_k(
    const float* __restrict__ A,
    const float* __restrict__ W0, const float* __restrict__ B0, float* __restrict__ C0,
    const float* __restrict__ W1, const float* __restrict__ B1, float* __restrict__ C1)
{
    __shared__ float As[32][260];       // [k][m] 256 rows + pad
    __shared__ float Ws[2][32][68];     // [k][n]
    const int bid = blockIdx.x;
    const int xcd = bid & 7;
    const int idx = bid >> 3;
    const int m0 = (xcd * 8 + (idx >> 3)) * 256;
    const int n0 = (idx & 7) * 64;
    const int tid = threadIdx.x;
    const int tx = tid & 15, ty = tid >> 4;   // tx: 4 n-cols, ty: 16 m-rows

    float acc[2][16][4];
#pragma unroll
    for (int o = 0; o < 2; ++o)
#pragma unroll
        for (int i = 0; i < 16; ++i)
#pragma unroll
            for (int j = 0; j < 4; ++j) acc[o][i][j] = 0.f;

    for (int kk = 0; kk < DD; kk += 32) {
        __syncthreads();
#pragma unroll
        for (int l = 0; l < 8; ++l) {             // A: 2048 float4
            int fid = l * 256 + tid;
            int row = fid >> 3, c4 = fid & 7;
            float4 v = *reinterpret_cast<const float4*>(&A[(size_t)(m0 + row) * DD + kk + c4 * 4]);
            As[c4 * 4 + 0][row] = v.x;
            As[c4 * 4 + 1][row] = v.y;
            As[c4 * 4 + 2][row] = v.z;
            As[c4 * 4 + 3][row] = v.w;
        }
        {
            int kr = tid >> 4, c4 = tid & 15;     // W: 512 float4 per output
            *reinterpret_cast<float4*>(&Ws[0][kr][c4 * 4]) =
                *reinterpret_cast<const float4*>(&W0[(size_t)(kk + kr) * DD + n0 + c4 * 4]);
            *reinterpret_cast<float4*>(&Ws[0][kr + 16][c4 * 4]) =
                *reinterpret_cast<const float4*>(&W0[(size_t)(kk + kr + 16) * DD + n0 + c4 * 4]);
            *reinterpret_cast<float4*>(&Ws[1][kr][c4 * 4]) =
                *reinterpret_cast<const float4*>(&W1[(size_t)(kk + kr) * DD + n0 + c4 * 4]);
            *reinterpret_cast<float4*>(&Ws[1][kr + 16][c4 * 4]) =
                *reinterpret_cast<const float4*>(&W1[(size_t)(kk + kr + 16) * DD + n0 + c4 * 4]);
        }
        __syncthreads();
#pragma unroll 4
        for (int k = 0; k < 32; ++k) {
            float4 a0 = *reinterpret_cast<const float4*>(&As[k][ty * 16]);
            float4 a1 = *reinterpret_cast<const float4*>(&As[k][ty * 16 + 4]);
            float4 a2 = *reinterpret_cast<const float4*>(&As[k][ty * 16 + 8]);
            float4 a3 = *reinterpret_cast<const float4*>(&As[k][ty * 16 + 12]);
            float a[16] = {a0.x, a0.y, a0.z, a0.w, a1.x, a1.y, a1.z, a1.w,
                           a2.x, a2.y, a2.z, a2.w, a3.x, a3.y, a3.z, a3.w};
            float4 w0 = *reinterpret_cast<const float4*>(&Ws[0][k][tx * 4]);
            float4 w1 = *reinterpret_cast<const float4*>(&Ws[1][k][tx * 4]);
#pragma unroll
            for (int i = 0; i < 16; ++i) {
                acc[0][i][0] = fmaf(a[i], w0.x, acc[0][i][0]);
                acc[0][i][1] = fmaf(a[i], w0.y, acc[0][i][1]);
                acc[0][i][2] = fmaf(a[i], w0.z, acc[0][i][2]);
                acc[0][i][3] = fmaf(a[i], w0.w, acc[0][i][3]);
                acc[1][i][0] = fmaf(a[i], w1.x, acc[1][i][0]);
                acc[1][i][1] = fmaf(a[i], w1.y, acc[1][i][1]);
                acc[1][i][2] = fmaf(a[i], w1.z, acc[1][i][2]);
                acc[1][i][3] = fmaf(a[i], w1.w, acc[1][i][3]);
            }
        }
    }
    float* Cp[2] = {C0, C1};
    const float* Bp[2] = {B0, B1};
#pragma unroll
    for (int o = 0; o < 2; ++o) {
        float4 bv = *reinterpret_cast<const float4*>(&Bp[o][n0 + tx * 4]);
#pragma unroll
        for (int i = 0; i < 16; ++i) {
            int row = m0 + ty * 16 + i;
            float4 o4 = {acc[o][i][0] + bv.x, acc[o][i][1] + bv.y,
                         acc[o][i][2] + bv.z, acc[o][i][3] + bv.w};
            *reinterpret_cast<float4*>(&Cp[o][(size_t)row * DD + n0 + tx * 4]) = o4;
        }
    }
}

// =======================================================================
// Generic f32 GEMM + bias (UNCHANGED — used for o-proj GEMMs)
// =======================================================================
template <int NOUT>
__global__ __launch_bounds__(256) void gemm_bias_k(
    const float* __restrict__ A,
    const float* __restrict__ W0, const float* __restrict__ B0, float* __restrict__ C0,
    const float* __restrict__ W1, const float* __restrict__ B1, float* __restrict__ C1,
    const float* __restrict__ W2, const float* __restrict__ B2, float* __restrict__ C2)
{
    __shared__ float As[32][64];          // [k][m]
    __shared__ float Ws[NOUT][32][64];    // [k][n]
    const int m0 = blockIdx.x * 64;
    const int n0 = blockIdx.y * 64;
    const int tid = threadIdx.x;
    const int tx = tid & 15, ty = tid >> 4;

    float acc[NOUT][4][4];
#pragma unroll
    for (int o = 0; o < NOUT; ++o)
#pragma unroll
        for (int i = 0; i < 4; ++i)
#pragma unroll
            for (int j = 0; j < 4; ++j) acc[o][i][j] = 0.f;

    const float* Wp[3] = {W0, W1, W2};

    for (int kk = 0; kk < DD; kk += 32) {
        __syncthreads();
#pragma unroll
        for (int l = 0; l < 2; ++l) {
            int fid = l * 256 + tid;          // 512 float4 of A tile
            int row = fid >> 3, c4 = fid & 7;
            float4 v = *reinterpret_cast<const float4*>(&A[(size_t)(m0 + row) * DD + kk + c4 * 4]);
            As[c4 * 4 + 0][row] = v.x;
            As[c4 * 4 + 1][row] = v.y;
            As[c4 * 4 + 2][row] = v.z;
            As[c4 * 4 + 3][row] = v.w;
        }
#pragma unroll
        for (int o = 0; o < NOUT; ++o) {
#pragma unroll
            for (int l = 0; l < 2; ++l) {
                int fid = l * 256 + tid;      // 512 float4 of W tile
                int kr = fid >> 4, c4 = fid & 15;
                *reinterpret_cast<float4*>(&Ws[o][kr][c4 * 4]) =
                    *reinterpret_cast<const float4*>(&Wp[o][(size_t)(kk + kr) * DD + n0 + c4 * 4]);
            }
        }
        __syncthreads();
#pragma unroll
        for (int k = 0; k < 32; ++k) {
            float4 av = *reinterpret_cast<const float4*>(&As[k][ty * 4]);
            float a[4] = {av.x, av.y, av.z, av.w};
#pragma unroll
            for (int o = 0; o < NOUT; ++o) {
                float4 wv = *reinterpret_cast<const float4*>(&Ws[o][k][tx * 4]);
#pragma unroll
                for (int i = 0; i < 4; ++i) {
                    acc[o][i][0] = fmaf(a[i], wv.x, acc[o][i][0]);
                    acc[o][i][1] = fmaf(a[i], wv.y, acc[o][i][1]);
                    acc[o][i][2] = fmaf(a[i], wv.z, acc[o][i][2]);
                    acc[o][i][3] = fmaf(a[i], wv.w, acc[o][i][3]);
                }
            }
        }
    }
    float* Cp[3] = {C0, C1, C2};
    const float* Bp[3] = {B0, B1, B2};
#pragma unroll
    for (int o = 0; o < NOUT; ++o) {
#pragma unroll
        for (int i = 0; i < 4; ++i) {
            int row = m0 + ty * 4 + i;
#pragma unroll
            for (int j = 0; j < 4; ++j) {
                int col = n0 + tx * 4 + j;
                Cp[o][(size_t)row * DD + col] = acc[o][i][j] + Bp[o][col];
            }
        }
    }
}

// =======================================================================
// Round 13: 3-output projection split across blocks: grid (16, 24),
// blockIdx.y>>3 selects which W/B/C; inner body IDENTICAL to
// gemm_bias_k<1> (same staging, same ascending-k fmaf, same 4x4
// microtile) -> bit-identical q2/k2/v2. 384 blocks (was 128) = 3x
// parallelism; A tile re-staged 3x from L2 (2 MB, free).
// =======================================================================
__global__ __launch_bounds__(256) void gemm_bias3_k(
    const float* __restrict__ A,
    const float* __restrict__ W0, const float* __restrict__ B0, float* __restrict__ C0,
    const float* __restrict__ W1, const float* __restrict__ B1, float* __restrict__ C1,
    const float* __restrict__ W2, const float* __restrict__ B2, float* __restrict__ C2)
{
    __shared__ float As[32][64];          // [k][m]
    __shared__ float Ws[32][64];          // [k][n]
    const int m0 = blockIdx.x * 64;
    const int o  = blockIdx.y >> 3;
    const int n0 = (blockIdx.y & 7) * 64;
    const int tid = threadIdx.x;
    const int tx = tid & 15, ty = tid >> 4;

    const float* Wp[3] = {W0, W1, W2};
    const float* Bp[3] = {B0, B1, B2};
    float*       Cp[3] = {C0, C1, C2};
    const float* W = Wp[o];

    float acc[4][4];
#pragma unroll
    for (int i = 0; i < 4; ++i)
#pragma unroll
        for (int j = 0; j < 4; ++j) acc[i][j] = 0.f;

    for (int kk = 0; kk < DD; kk += 32) {
        __syncthreads();
#pragma unroll
        for (int l = 0; l < 2; ++l) {
            int fid = l * 256 + tid;          // 512 float4 of A tile
            int row = fid >> 3, c4 = fid & 7;
            float4 v = *reinterpret_cast<const float4*>(&A[(size_t)(m0 + row) * DD + kk + c4 * 4]);
            As[c4 * 4 + 0][row] = v.x;
            As[c4 * 4 + 1][row] = v.y;
            As[c4 * 4 + 2][row] = v.z;
            As[c4 * 4 + 3][row] = v.w;
        }
#pragma unroll
        for (int l = 0; l < 2; ++l) {
            int fid = l * 256 + tid;          // 512 float4 of W tile
            int kr = fid >> 4, c4 = fid & 15;
            *reinterpret_cast<float4*>(&Ws[kr][c4 * 4]) =
                *reinterpret_cast<const float4*>(&W[(size_t)(kk + kr) * DD + n0 + c4 * 4]);
        }
        __syncthreads();
#pragma unroll
        for (int k = 0; k < 32; ++k) {
            float4 av = *reinterpret_cast<const float4*>(&As[k][ty * 4]);
            float a[4] = {av.x, av.y, av.z, av.w};
            float4 wv = *reinterpret_cast<const float4*>(&Ws[k][tx * 4]);
#pragma unroll
            for (int i = 0; i < 4; ++i) {
                acc[i][0] = fmaf(a[i], wv.x, acc[i][0]);
                acc[i][1] = fmaf(a[i], wv.y, acc[i][1]);
                acc[i][2] = fmaf(a[i], wv.z, acc[i][2]);
                acc[i][3] = fmaf(a[i], wv.w, acc[i][3]);
            }
        }
    }
#pragma unroll
    for (int i = 0; i < 4; ++i) {
        int row = m0 + ty * 4 + i;
#pragma unroll
        for (int j = 0; j < 4; ++j) {
            int col = n0 + tx * 4 + j;
            Cp[o][(size_t)row * DD + col] = acc[i][j] + Bp[o][col];
        }
    }
}

// =======================================================================
// MHA core — REVERTED to round-7/10 plain LDS form (best measured).
// =======================================================================
__global__ __launch_bounds__(128) void attn_k(
    const float* __restrict__ q, int q_shared,
    const float* __restrict__ kmat, const float* __restrict__ vmat,
    float* __restrict__ outp, int slen)
{
    __shared__ float qs[32][68];
    __shared__ float kst[64][68]; // [e][j] (transposed)
    __shared__ float vs[64][68];  // [j][c]
    int bid = blockIdx.x;
    int b = bid >> 4, h = (bid >> 1) & 7, half = bid & 1;
    int tid = threadIdx.x;
    const float* qb = q + (q_shared ? (size_t)0 : (size_t)b * 64 * DD);
    const float* kb = kmat + (size_t)b * slen * DD;
    const float* vb = vmat + (size_t)b * slen * DD;

#pragma unroll
    for (int l = 0; l < 4; ++l) {               // 32 rows x 16 float4
        int fid = l * 128 + tid;
        int r = fid >> 4, c4 = fid & 15;
        *reinterpret_cast<float4*>(&qs[r][c4 * 4]) =
            *reinterpret_cast<const float4*>(&qb[(size_t)(half * 32 + r) * DD + h * HDIM + c4 * 4]);
    }
    const int row = tid >> 2, c4 = tid & 3;     // row 0..31
    float acc[16];
#pragma unroll
    for (int i = 0; i < 16; ++i) acc[i] = 0.f;
    float m_run = -INFINITY, l_run = 0.f;

    for (int s0 = 0; s0 < slen; s0 += 64) {
        __syncthreads();
#pragma unroll
        for (int l = 0; l < 8; ++l) {           // 64 rows x 16 float4
            int fid = l * 128 + tid;
            int r = fid >> 4, cc = fid & 15;
            float4 t4 = *reinterpret_cast<const float4*>(&kb[(size_t)(s0 + r) * DD + h * HDIM + cc * 4]);
            kst[cc * 4 + 0][r] = t4.x;
            kst[cc * 4 + 1][r] = t4.y;
            kst[cc * 4 + 2][r] = t4.z;
            kst[cc * 4 + 3][r] = t4.w;
            *reinterpret_cast<float4*>(&vs[r][cc * 4]) =
                *reinterpret_cast<const float4*>(&vb[(size_t)(s0 + r) * DD + h * HDIM + cc * 4]);
        }
        __syncthreads();

        float p[16];
#pragma unroll
        for (int i = 0; i < 16; ++i) p[i] = 0.f;
#pragma unroll 4
        for (int e = 0; e < 64; ++e) {
            float qv = qs[row][e];
#pragma unroll
            for (int j4 = 0; j4 < 4; ++j4) {
                float4 k4 = *reinterpret_cast<const float4*>(&kst[e][c4 * 16 + j4 * 4]);
                p[j4 * 4 + 0] = fmaf(qv, k4.x, p[j4 * 4 + 0]);
                p[j4 * 4 + 1] = fmaf(qv, k4.y, p[j4 * 4 + 1]);
                p[j4 * 4 + 2] = fmaf(qv, k4.z, p[j4 * 4 + 2]);
                p[j4 * 4 + 3] = fmaf(qv, k4.w, p[j4 * 4 + 3]);
            }
        }
#pragma unroll
        for (int i = 0; i < 16; ++i) p[i] *= 0.125f;   // / sqrt(64), exact
        float mx = p[0];
#pragma unroll
        for (int i = 1; i < 16; ++i) mx = fmaxf(mx, p[i]);
        mx = fmaxf(mx, __shfl_xor(mx, 1));
        mx = fmaxf(mx, __shfl_xor(mx, 2));
        float m_new = fmaxf(m_run, mx);
        float scale = expf(m_run - m_new);             // 0 on first tile
        float lsum = 0.f;
#pragma unroll
        for (int i = 0; i < 16; ++i) { p[i] = expf(p[i] - m_new); lsum += p[i]; }
        lsum += __shfl_xor(lsum, 1);
        lsum += __shfl_xor(lsum, 2);
        l_run = l_run * scale + lsum;
        m_run = m_new;
#pragma unroll
        for (int i = 0; i < 16; ++i) acc[i] *= scale;

#pragma unroll 16
        for (int j = 0; j < 64; ++j) {
            float pv = __shfl(p[j & 15], j >> 4, 4);   // owner lane in quad
#pragma unroll
            for (int u = 0; u < 4; ++u) {
                float4 v4 = *reinterpret_cast<const float4*>(&vs[j][c4 * 16 + u * 4]);
                acc[u * 4 + 0] = fmaf(pv, v4.x, acc[u * 4 + 0]);
                acc[u * 4 + 1] = fmaf(pv, v4.y, acc[u * 4 + 1]);
                acc[u * 4 + 2] = fmaf(pv, v4.z, acc[u * 4 + 2]);
                acc[u * 4 + 3] = fmaf(pv, v4.w, acc[u * 4 + 3]);
            }
        }
    }
#pragma unroll
    for (int i = 0; i < 16; ++i) acc[i] /= l_run;
#pragma unroll
    for (int u = 0; u < 4; ++u) {
        float4 o4 = {acc[u * 4 + 0], acc[u * 4 + 1], acc[u * 4 + 2], acc[u * 4 + 3]};
        *reinterpret_cast<float4*>(&outp[((size_t)b * 64 + half * 32 + row) * DD + h * HDIM + c4 * 16 + u * 4]) = o4;
    }
}

// =======================================================================
// LayerNorm (UNCHANGED)
// =======================================================================
__device__ __forceinline__ float block_sum256(float v, float* sb)
{
#pragma unroll
    for (int off = 32; off; off >>= 1) v += __shfl_down(v, off);
    __syncthreads();
    if ((threadIdx.x & 63) == 0) sb[threadIdx.x >> 6] = v;
    __syncthreads();
    return (sb[0] + sb[1]) + (sb[2] + sb[3]);
}

__global__ __launch_bounds__(256) void ln_k(
    const float* __restrict__ res, int res_shared, const float* __restrict__ y,
    const float* __restrict__ g, const float* __restrict__ bb,
    float* __restrict__ out, float* __restrict__ out2, double* __restrict__ e2)
{
    __shared__ float sbuf[4];
    __shared__ double dbuf[4];
    int row = blockIdx.x;
    int t = threadIdx.x;
    const float* rp = res + (size_t)(res_shared ? (row & 63) : row) * DD;
    const float* yp = y + (size_t)row * DD;
    float x0 = rp[t] + yp[t];
    float x1 = rp[t + 256] + yp[t + 256];
    float m = block_sum256(x0 + x1, sbuf) / 512.0f;
    float d0 = x0 - m, d1 = x1 - m;
    float v = block_sum256(d0 * d0 + d1 * d1, sbuf) / 512.0f;
    float s = sqrtf(v + 1e-5f);
    float o0 = d0 / s * g[t] + bb[t];
    float o1 = d1 / s * g[t + 256] + bb[t + 256];
    out[(size_t)row * DD + t] = o0;
    out[(size_t)row * DD + t + 256] = o1;
    if (out2) {
        out2[(size_t)row * DD + t] = o0;
        out2[(size_t)row * DD + t + 256] = o1;
    }
    if (e2) {
        double sd = (double)o0 * o0 + (double)o1 * o1;
#pragma unroll
        for (int off = 32; off; off >>= 1) sd += __shfl_down(sd, off);
        if ((t & 63) == 0) dbuf[t >> 6] = sd;
        __syncthreads();
        if (t == 0) e2[row] = (dbuf[0] + dbuf[1]) + (dbuf[2] + dbuf[3]);
    }
}

// =======================================================================
// VQ (UNCHANGED from round 4)
// =======================================================================
__global__ __launch_bounds__(512) void vq_k(
    const float* __restrict__ z, const float* __restrict__ emb,
    const double* __restrict__ e2,
    float* __restrict__ zq, float* __restrict__ enc, float* __restrict__ idxo,
    double* __restrict__ lossp, int* __restrict__ counts)
{
    __shared__ float zs[32][68];   // [k][row]
    __shared__ float es[32][68];   // [k][code]
    __shared__ int   kms[64];
    __shared__ double dred[8];
    __shared__ int   cnt_s[64];

    const int bid = blockIdx.x;
    const int b   = bid >> 5;
    const int m0  = (bid & 31) * 64;
    const int tid = threadIdx.x;
    const int tx  = tid & 15, ty = tid >> 4;

    const float* zb = z   + ((size_t)b * TTOK + m0) * DD;
    const float* eb = emb + (size_t)b * NE * DD;

    double acc[2][4];
#pragma unroll
    for (int r = 0; r < 2; ++r)
#pragma unroll
        for (int j = 0; j < 4; ++j) acc[r][j] = 0.0;

    const int lrow = tid >> 3, lc4 = tid & 7;

    for (int kk = 0; kk < DD; kk += 32) {
        __syncthreads();
        {
            float4 t4 = *reinterpret_cast<const float4*>(&zb[(size_t)lrow * DD + kk + lc4 * 4]);
            zs[lc4 * 4 + 0][lrow] = t4.x;
            zs[lc4 * 4 + 1][lrow] = t4.y;
            zs[lc4 * 4 + 2][lrow] = t4.z;
            zs[lc4 * 4 + 3][lrow] = t4.w;
            float4 e4 = *reinterpret_cast<const float4*>(&eb[(size_t)lrow * DD + kk + lc4 * 4]);
            es[lc4 * 4 + 0][lrow] = e4.x;
            es[lc4 * 4 + 1][lrow] = e4.y;
            es[lc4 * 4 + 2][lrow] = e4.z;
            es[lc4 * 4 + 3][lrow] = e4.w;
        }
        __syncthreads();
#pragma unroll
        for (int k = 0; k < 32; ++k) {
            float2 zv = *reinterpret_cast<const float2*>(&zs[k][ty * 2]);
            float4 ev = *reinterpret_cast<const float4*>(&es[k][tx * 4]);
            double z0 = (double)zv.x, z1 = (double)zv.y;
            double e0 = (double)ev.x, e1 = (double)ev.y;
            double e2d = (double)ev.z, e3 = (double)ev.w;
            acc[0][0] = fma(z0, e0, acc[0][0]);
            acc[0][1] = fma(z0, e1, acc[0][1]);
            acc[0][2] = fma(z0, e2d, acc[0][2]);
            acc[0][3] = fma(z0, e3, acc[0][3]);
            acc[1][0] = fma(z1, e0, acc[1][0]);
            acc[1][1] = fma(z1, e1, acc[1][1]);
            acc[1][2] = fma(z1, e2d, acc[1][2]);
            acc[1][3] = fma(z1, e3, acc[1][3]);
        }
    }

    double e2v[4];
#pragma unroll
    for (int j = 0; j < 4; ++j) e2v[j] = e2[b * NE + tx * 4 + j];

    double vmin[2]; int imin[2];
#pragma unroll
    for (int r = 0; r < 2; ++r) {
        vmin[r] = e2v[0] - 2.0 * acc[r][0];
        imin[r] = tx * 4;
#pragma unroll
        for (int j = 1; j < 4; ++j) {
            double s = e2v[j] - 2.0 * acc[r][j];
            if (s < vmin[r]) { vmin[r] = s; imin[r] = tx * 4 + j; }
        }
    }
#pragma unroll
    for (int off = 1; off < 16; off <<= 1) {
#pragma unroll
        for (int r = 0; r < 2; ++r) {
            double ov = __shfl_xor(vmin[r], off);
            int    oi = __shfl_xor(imin[r], off);
            if (ov < vmin[r] || (ov == vmin[r] && oi < imin[r])) { vmin[r] = ov; imin[r] = oi; }
        }
    }
    if (tid < 64) cnt_s[tid] = 0;
    if (tx == 0) { kms[ty * 2] = imin[0]; kms[ty * 2 + 1] = imin[1]; }
    __syncthreads();
    if (tid < 64) atomicAdd(&cnt_s[kms[tid]], 1);

    const int row = tid >> 3, p = tid & 7;
    const int km  = kms[row];
    const float* zr = &zb[(size_t)row * DD];
    const float* er = &eb[(size_t)km * DD];
    const size_t grow = (size_t)b * TTOK + m0 + row;
    float* zqr = zq + grow * DD;
    double lsum = 0.0;
#pragma unroll 4
    for (int i = 0; i < 16; ++i) {
        int col = (i * 8 + p) * 4;
        float4 zv = *reinterpret_cast<const float4*>(&zr[col]);
        float4 ev = *reinterpret_cast<const float4*>(&er[col]);
        float d0 = ev.x - zv.x, d1 = ev.y - zv.y, d2 = ev.z - zv.z, d3 = ev.w - zv.w;
        lsum += (double)d0 * d0 + (double)d1 * d1 + (double)d2 * d2 + (double)d3 * d3;
        float4 o4 = {zv.x + d0, zv.y + d1, zv.z + d2, zv.w + d3};
        *reinterpret_cast<float4*>(&zqr[col]) = o4;
    }
    {
        float* ep = enc + grow * NE + p * 8;
        float4 o0, o1;
        o0.x = (p * 8 + 0 == km) ? 1.f : 0.f;
        o0.y = (p * 8 + 1 == km) ? 1.f : 0.f;
        o0.z = (p * 8 + 2 == km) ? 1.f : 0.f;
        o0.w = (p * 8 + 3 == km) ? 1.f : 0.f;
        o1.x = (p * 8 + 4 == km) ? 1.f : 0.f;
        o1.y = (p * 8 + 5 == km) ? 1.f : 0.f;
        o1.z = (p * 8 + 6 == km) ? 1.f : 0.f;
        o1.w = (p * 8 + 7 == km) ? 1.f : 0.f;
        *reinterpret_cast<float4*>(ep)     = o0;
        *reinterpret_cast<float4*>(ep + 4) = o1;
    }
    if (tid < 64) idxo[(size_t)b * TTOK + m0 + tid] = (float)kms[tid];

#pragma unroll
    for (int off = 32; off; off >>= 1) lsum += __shfl_down(lsum, off);
    if ((tid & 63) == 0) dred[tid >> 6] = lsum;
    __syncthreads();
    if (tid == 0) {
        double t = 0.0;
#pragma unroll
        for (int w = 0; w < 8; ++w) t += dred[w];
        lossp[bid] = t;
    }
    if (tid < 64 && cnt_s[tid]) atomicAdd(&counts[tid], cnt_s[tid]);
}

// =======================================================================
// Finalize (UNCHANGED)
// =======================================================================
__global__ void fin_k(const double* __restrict__ lossp, const int* __restrict__ counts,
                      float* __restrict__ loss_out, float* __restrict__ perp_out)
{
    int tid = threadIdx.x;  // 64 threads
    if (tid == 0) {
        double tot = 0.0;
        for (int i = 0; i < 512; ++i) tot += lossp[i];
        loss_out[0] = (float)(1.5 * tot / 16777216.0);   // (BETA+1)*mean
    }
    float e = counts[tid] / 32768.0f;
    float term = e * logf(e + 1e-10f);
#pragma unroll
    for (int off = 32; off; off >>= 1) term += __shfl_down(term, off);
    if (tid == 0) perp_out[0] = expf(-term);
}

// =======================================================================
extern "C" void kernel_launch(void* const* d_in, const int* in_sizes, int n_in,
                              void* d_out, int out_size, void* d_ws, size_t ws_size,
                              hipStream_t stream)
{
    (void)in_sizes; (void)n_in; (void)out_size; (void)ws_size;
    const float* x_enc = (const float*)d_in[0];
    const float* z     = (const float*)d_in[1];
    const float* tab   = (const float*)d_in[2];
    const float* wq1 = (const float*)d_in[3];  const float* bq1 = (const float*)d_in[4];
    const float* wk1 = (const float*)d_in[5];  const float* bk1 = (const float*)d_in[6];
    const float* wv1 = (const float*)d_in[7];  const float* bv1 = (const float*)d_in[8];
    const float* wo1 = (const float*)d_in[9];  const float* bo1 = (const float*)d_in[10];
    const float* wq2 = (const float*)d_in[11]; const float* bq2 = (const float*)d_in[12];
    const float* wk2 = (const float*)d_in[13]; const float* bk2 = (const float*)d_in[14];
    const float* wv2 = (const float*)d_in[15]; const float* bv2 = (const float*)d_in[16];
    const float* wo2 = (const float*)d_in[17]; const float* bo2 = (const float*)d_in[18];
    const float* ln2g = (const float*)d_in[19]; const float* ln2b = (const float*)d_in[20];
    const float* ln1g = (const float*)d_in[21]; const float* ln1b = (const float*)d_in[22];

    float* ws  = (float*)d_ws;
    float* out = (float*)d_out;

    float* k1   = ws + WS_K1;
    float* v1   = ws + WS_V1;
    float* emb0 = ws + WS_EMB0;
    float* q1   = ws + WS_Q1;
    float* att1 = ws + WS_ATT1;
    float* emb1 = ws + WS_EMB1;
    float* q2   = ws + WS_Q2;
    float* k2   = ws + WS_K2;
    float* v2   = ws + WS_V2;
    float* att2 = ws + WS_ATT2;
    float* ybuf = ws + WS_YBUF;
    float* embf = ws + WS_EMBF;
    double* e2    = (double*)(ws + WS_E2);
    double* lossp = (double*)(ws + WS_LOSSP);
    int*    cnts  = (int*)(ws + WS_CNT);

    hipMemsetAsync(cnts, 0, NE * sizeof(int), stream);

    pe_emb0_k<<<64, 256, 0, stream>>>(tab, emb0);

    gemm_q1_k<<<128, 256, 0, stream>>>(emb0, wq1, bq1, q1);
    gemm_kv_k<<<512, 256, 0, stream>>>(x_enc, wk1, bk1, k1,
                                       wv1, bv1, v1);
    attn_k<<<256, 128, 0, stream>>>(q1, 1, k1, v1, att1, SENC);

    gemm_bias_k<1><<<dim3(16, 8), 256, 0, stream>>>(att1, wo1, bo1, ybuf,
                                                    nullptr, nullptr, nullptr,
                                                    nullptr, nullptr, nullptr);
    ln_k<<<1024, 256, 0, stream>>>(emb0, 1, ybuf, ln1g, ln1b, emb1, nullptr, nullptr);

    gemm_bias3_k<<<dim3(16, 24), 256, 0, stream>>>(emb1, wq2, bq2, q2,
                                                   wk2, bk2, k2,
                                                   wv2, bv2, v2);
    attn_k<<<256, 128, 0, stream>>>(q2, 0, k2, v2, att2, 64);

    gemm_bias_k<1><<<dim3(16, 8), 256, 0, stream>>>(att2, wo2, bo2, ybuf,
                                                    nullptr, nullptr, nullptr,
                                                    nullptr, nullptr, nullptr);
    ln_k<<<1024, 256, 0, stream>>>(emb1, 0, ybuf, ln2g, ln2b, embf, out + OUT_EMB, e2);

    vq_k<<<512, 512, 0, stream>>>(z, embf, e2,
                                  out + OUT_ZQ, out + OUT_ENC, out + OUT_IDX,
                                  lossp, cnts);
    fin_k<<<1, 64, 0, stream>>>(lossp, cnts, out + OUT_LOSS, out + OUT_PERP);
}